// Round 9
// baseline (195.811 us; speedup 1.0000x reference)
//
#include <hip/hip_runtime.h>

__device__ __forceinline__ float fexp2(float x) { return __builtin_amdgcn_exp2f(x); }
__device__ __forceinline__ float flog2(float x) { return __builtin_amdgcn_logf(x); }

__device__ __forceinline__ float s2lin(float c) {
    float p = fexp2(flog2((c + 0.055f) * (1.0f / 1.055f)) * 2.4f);
    return c > 0.04045f ? p : c * (1.0f / 12.92f);
}

__device__ __forceinline__ float labf(float t) {
    float p = fexp2(flog2(t) * (1.0f / 3.0f));
    return t > 0.008856f ? p : 7.787f * t + (16.0f / 116.0f);
}

__device__ __forceinline__ void px(float r, float g, float b,
                                   float& L, float& a01, float& b01) {
    float lr = s2lin(r), lg = s2lin(g), lb = s2lin(b);
    // RGB2XYZ rows pre-divided by D65 white (0.95047, 1.0, 1.08883)
    float X = 0.43395300f * lr + 0.37621900f * lg + 0.18982460f * lb;
    float Y = 0.21267100f * lr + 0.71516000f * lg + 0.07216900f * lb;
    float Z = 0.01775660f * lr + 0.10946970f * lg + 0.87270740f * lb;
    float fx = labf(X), fy = labf(Y), fz = labf(Z);
    L   = 116.0f * fy - 16.0f;                              // L in [0,100]
    a01 = (500.0f * (fx - fy) + 128.0f) * (1.0f / 255.0f);
    b01 = (200.0f * (fy - fz) + 128.0f) * (1.0f / 255.0f);
}

// L only: Y row + one labf. Bitwise-identical to px()'s L (same ops, same
// order) -- R8 verified the k1/k2 consistency passes.
__device__ __forceinline__ float Lonly(float r, float g, float b) {
    float lr = s2lin(r), lg = s2lin(g), lb = s2lin(b);
    float Y = 0.21267100f * lr + 0.71516000f * lg + 0.07216900f * lb;
    return 116.0f * labf(Y) - 16.0f;
}

// Two-pass recompute (R8 structure) with BARRIER-FREE register streaming:
// no LDS staging (k1 never reuses staged data; the stage->barrier->compute->
// barrier skeleton is why R0/R8 pairs sat at ~3 TB/s). 2048 blocks x 256 thr,
// 4 blocks/image, 16 px/thread in 12 float4 via the R3-proven chunk pipeline
// (no spill at default bounds). k2 re-reads x from Infinity Cache (96 MB
// sticks in 256 MB L3 across the kernel boundary) and rescales inline.

// chunk of 4 px in 3 float4: {r0,g0,b0,r1},{g1,b1,r2,g2},{b2,r3,g3,b3}
__device__ __forceinline__ void chunk_min(const float4& A, const float4& B,
                                          const float4& C, float& m1, float& m2) {
    float L;
    L = Lonly(A.x, A.y, A.z); m1 = fminf(m1, L); m2 = fminf(m2, 100.0f - L);
    L = Lonly(A.w, B.x, B.y); m1 = fminf(m1, L); m2 = fminf(m2, 100.0f - L);
    L = Lonly(B.z, B.w, C.x); m1 = fminf(m1, L); m2 = fminf(m2, 100.0f - L);
    L = Lonly(C.y, C.z, C.w); m1 = fminf(m1, L); m2 = fminf(m2, 100.0f - L);
}

__global__ __launch_bounds__(256) void k1_min(const float* __restrict__ x,
                                              float* __restrict__ hdr) {
    const int bid = blockIdx.x, t = threadIdx.x;
    const int img = bid >> 2, sub = bid & 3;
    const float4* __restrict__ in4 =
        (const float4*)x + (size_t)img * 12288 + (size_t)sub * 3072;

    float m1 = 3.4e38f, m2 = 3.4e38f;          // min(L), min(100-L)
    // 2-chunk software pipeline: next chunk's 3 loads in flight under compute
    float4 A = in4[3 * t], B = in4[3 * t + 1], C = in4[3 * t + 2];
#pragma unroll
    for (int c = 0; c < 4; ++c) {
        float4 An, Bn, Cn;
        if (c < 3) {
            const int o = (c + 1) * 768 + 3 * t;
            An = in4[o]; Bn = in4[o + 1]; Cn = in4[o + 2];
        }
        chunk_min(A, B, C, m1, m2);
        A = An; B = Bn; C = Cn;
    }

    // wave reduce (64 lanes), then 4-wave LDS reduce (only sync in kernel)
#pragma unroll
    for (int m = 32; m; m >>= 1) {
        m1 = fminf(m1, __shfl_xor(m1, m, 64));
        m2 = fminf(m2, __shfl_xor(m2, m, 64));
    }
    __shared__ float sm[8];
    if ((t & 63) == 0) { sm[(t >> 6) * 2] = m1; sm[(t >> 6) * 2 + 1] = m2; }
    __syncthreads();
    if (t == 0) {
        hdr[((size_t)img * 4 + sub) * 2] =
            fminf(fminf(sm[0], sm[2]), fminf(sm[4], sm[6]));
        hdr[((size_t)img * 4 + sub) * 2 + 1] =
            fminf(fminf(sm[1], sm[3]), fminf(sm[5], sm[7]));
    }
}

__global__ __launch_bounds__(256) void k2_full(const float* __restrict__ x,
                                               float* __restrict__ out,
                                               const float* __restrict__ hdr0) {
    const int bid = blockIdx.x, t = threadIdx.x;
    const int img = bid >> 2, sub = bid & 3;

    const float* hdr = hdr0 + (size_t)img * 8;  // 8 floats, uniform -> scalar loads
    float Lmin = 3.4e38f, m2 = 3.4e38f;
#pragma unroll
    for (int i = 0; i < 4; ++i) {
        Lmin = fminf(Lmin, hdr[2 * i]);
        m2   = fminf(m2,   hdr[2 * i + 1]);
    }
    const float s = 1.0f / ((100.0f - m2) - Lmin);

    const size_t base4 = (size_t)img * 12288 + (size_t)sub * 3072;
    const float4* __restrict__ in4 = (const float4*)x + base4;    // L3-hot
    float4* __restrict__ o4 = (float4*)out + base4;

    float4 A = in4[3 * t], B = in4[3 * t + 1], C = in4[3 * t + 2];
#pragma unroll
    for (int c = 0; c < 4; ++c) {
        float4 An, Bn, Cn;
        if (c < 3) {
            const int o = (c + 1) * 768 + 3 * t;
            An = in4[o]; Bn = in4[o + 1]; Cn = in4[o + 2];
        }
        // compute in place, rescale L inline, store per-chunk (low reg pressure)
        float L, a, b;
        px(A.x, A.y, A.z, L, a, b); A.x = (L - Lmin) * s; A.y = a; A.z = b;
        px(A.w, B.x, B.y, L, a, b); A.w = (L - Lmin) * s; B.x = a; B.y = b;
        px(B.z, B.w, C.x, L, a, b); B.z = (L - Lmin) * s; B.w = a; C.x = b;
        px(C.y, C.z, C.w, L, a, b); C.y = (L - Lmin) * s; C.z = a; C.w = b;
        const int o = c * 768 + 3 * t;
        o4[o] = A; o4[o + 1] = B; o4[o + 2] = C;
        A = An; B = Bn; C = Cn;
    }
}

// ---- fallback: round-1 monolith (verified, 68 us) if ws < 16 KB ----
typedef unsigned int uint32;
__global__ __launch_bounds__(1024) void k_fb(const float* __restrict__ x,
                                             float* __restrict__ out) {
    const int img = blockIdx.x, t = threadIdx.x;
    const size_t base = (size_t)img * 49152;
    const float* __restrict__ in = x + base;
    float* __restrict__ o = out + base;

    uint32 pk[16];
    float m1 = 3.4e38f, m2 = 3.4e38f;
#pragma unroll
    for (int i = 0; i < 16; ++i) {
        const int p = t + (i << 10);
        const float* q = in + 3 * p;
        float L, a01, b01;
        px(q[0], q[1], q[2], L, a01, b01);
        m1 = fminf(m1, L);
        m2 = fminf(m2, 100.0f - L);
        uint32 au = (uint32)(a01 * 255.0f + 0.5f);
        uint32 bu = (uint32)(b01 * 255.0f + 0.5f);
        unsigned short hb = __builtin_bit_cast(unsigned short, (_Float16)L);
        pk[i] = au | (bu << 8) | ((uint32)hb << 16);
    }
#pragma unroll
    for (int m = 32; m; m >>= 1) {
        m1 = fminf(m1, __shfl_xor(m1, m, 64));
        m2 = fminf(m2, __shfl_xor(m2, m, 64));
    }
    __shared__ float sm[32];
    if ((t & 63) == 0) { sm[(t >> 6) * 2] = m1; sm[(t >> 6) * 2 + 1] = m2; }
    __syncthreads();
    float Lmin = 3.4e38f, M2 = 3.4e38f;
#pragma unroll
    for (int i = 0; i < 16; ++i) {
        Lmin = fminf(Lmin, sm[2 * i]);
        M2   = fminf(M2,   sm[2 * i + 1]);
    }
    const float s = 1.0f / ((100.0f - M2) - Lmin);
#pragma unroll
    for (int i = 0; i < 16; ++i) {
        const int p = t + (i << 10);
        const uint32 v = pk[i];
        float* q = o + 3 * p;
        q[0] = ((float)__builtin_bit_cast(_Float16, (unsigned short)(v >> 16)) - Lmin) * s;
        q[1] = (float)(v & 255u) * (1.0f / 255.0f);
        q[2] = (float)((v >> 8) & 255u) * (1.0f / 255.0f);
    }
}

extern "C" void kernel_launch(void* const* d_in, const int* in_sizes, int n_in,
                              void* d_out, int out_size, void* d_ws, size_t ws_size,
                              hipStream_t stream) {
    (void)in_sizes; (void)n_in; (void)out_size;
    const float* x = (const float*)d_in[0];
    float* out = (float*)d_out;
    if (ws_size >= 2048ull * 2ull * sizeof(float)) {
        float* hdr = (float*)d_ws;
        k1_min<<<2048, 256, 0, stream>>>(x, hdr);
        k2_full<<<2048, 256, 0, stream>>>(x, out, hdr);
    } else {
        k_fb<<<512, 1024, 0, stream>>>(x, out);
    }
}